// Round 6
// baseline (386.868 us; speedup 1.0000x reference)
//
#include <hip/hip_runtime.h>
#include <math.h>

#define B_ 2
#define T_ 2048
#define C_ 2048
#define H_ 16
#define HKV_ 4
#define D_ 128
#define G_ (H_ / HKV_)
#define GK 2048   // GEMM K dim (== C_)

typedef float f32x4 __attribute__((ext_vector_type(4)));
typedef __bf16 bf16x8 __attribute__((ext_vector_type(8)));

static __device__ __forceinline__ f32x4 mfma16(bf16x8 a, bf16x8 b, f32x4 c) {
    return __builtin_amdgcn_mfma_f32_16x16x32_bf16(a, b, c, 0, 0, 0);
}

// async global->LDS, 16 B per lane; lds base must be wave-uniform (HW adds lane*16)
static __device__ __forceinline__ void gload16(const __bf16* g, __bf16* l) {
    __builtin_amdgcn_global_load_lds(
        (const __attribute__((address_space(1))) unsigned int*)g,
        (__attribute__((address_space(3))) unsigned int*)l,
        16, 0, 0);
}

// ---------------------------------------------------------------------------
// x fp32 -> bf16, 8 elems/thread
// ---------------------------------------------------------------------------
__global__ __launch_bounds__(256)
void conv_f32_bf16(const float* __restrict__ src, __bf16* __restrict__ dst, int n8)
{
    const int i = blockIdx.x * blockDim.x + threadIdx.x;
    if (i >= n8) return;
    const float4 a = *(const float4*)&src[(size_t)i * 8];
    const float4 b = *(const float4*)&src[(size_t)i * 8 + 4];
    bf16x8 o;
    o[0] = (__bf16)a.x; o[1] = (__bf16)a.y; o[2] = (__bf16)a.z; o[3] = (__bf16)a.w;
    o[4] = (__bf16)b.x; o[5] = (__bf16)b.y; o[6] = (__bf16)b.z; o[7] = (__bf16)b.w;
    *(bf16x8*)&dst[(size_t)i * 8] = o;
}

// ---------------------------------------------------------------------------
// W fp32 [K][N] -> bf16 [N][K]  (transpose + convert), 32x32 LDS tile
// ---------------------------------------------------------------------------
__global__ __launch_bounds__(256)
void tconv(const float* __restrict__ src, __bf16* __restrict__ dst, int N)
{
    __shared__ __bf16 tl[32][34];
    const int tx = threadIdx.x;   // 0..31
    const int ty = threadIdx.y;   // 0..7
    const int k0 = blockIdx.x * 32;
    const int n0 = blockIdx.y * 32;

    #pragma unroll
    for (int i = 0; i < 4; ++i) {
        const int r = ty + i * 8;
        tl[r][tx] = (__bf16)src[(size_t)(k0 + r) * N + n0 + tx];
    }
    __syncthreads();
    #pragma unroll
    for (int i = 0; i < 4; ++i) {
        const int r = ty + i * 8;
        dst[(size_t)(n0 + r) * GK + k0 + tx] = tl[tx][r];
    }
}

// ---------------------------------------------------------------------------
// bf16 MFMA GEMM core (m97 structure): C[128x128] = A[M][K] * Bt[N][K]^T.
// 256 thr = 4 waves (2x2), each wave 64x64 = 4x4 frags. BK=64.
// Staging via global_load_lds (16B/lane) into LINEAR [row][64] LDS;
// 2 barriers per K-step (compiler drains vmcnt before s_barrier).
// ds_read_b128 fragment reads carry the known m97 bank alias (accepted).
// ---------------------------------------------------------------------------
#define GEMM_MAIN(At, Bt)                                                       \
    __shared__ __bf16 As[128 * 64];                                             \
    __shared__ __bf16 Bs[128 * 64];                                             \
    const int tid = threadIdx.x;                                                \
    const int wave = tid >> 6, lane = tid & 63;                                 \
    const int a = lane & 15, bq = lane >> 4;                                    \
    const int wr = wave >> 1, wc = wave & 1;                                    \
    const int srow = wave * 32 + (lane >> 3);  /* + i*8 */                      \
    const int scol = (lane & 7) * 8;                                            \
    f32x4 acc[4][4];                                                            \
    _Pragma("unroll")                                                           \
    for (int mi = 0; mi < 4; ++mi)                                              \
        _Pragma("unroll")                                                       \
        for (int ni = 0; ni < 4; ++ni) acc[mi][ni] = (f32x4){0.f,0.f,0.f,0.f};  \
    for (int k0 = 0; k0 < GK; k0 += 64) {                                       \
        __syncthreads();   /* prior tile's reads complete */                    \
        _Pragma("unroll")                                                       \
        for (int i = 0; i < 4; ++i) {                                           \
            gload16(&(At)[(size_t)(srow + i * 8) * GK + k0 + scol],             \
                    &As[(wave * 32 + i * 8) * 64]);                             \
            gload16(&(Bt)[(size_t)(srow + i * 8) * GK + k0 + scol],             \
                    &Bs[(wave * 32 + i * 8) * 64]);                             \
        }                                                                       \
        __syncthreads();   /* drains vmcnt -> LDS writes visible */             \
        _Pragma("unroll")                                                       \
        for (int ks = 0; ks < 2; ++ks) {                                        \
            bf16x8 af[4], bfr[4];                                               \
            _Pragma("unroll")                                                   \
            for (int mi = 0; mi < 4; ++mi)                                      \
                af[mi] = *(const bf16x8*)&As[(wr*64 + mi*16 + a) * 64 + ks*32 + bq*8]; \
            _Pragma("unroll")                                                   \
            for (int ni = 0; ni < 4; ++ni)                                      \
                bfr[ni] = *(const bf16x8*)&Bs[(wc*64 + ni*16 + a) * 64 + ks*32 + bq*8]; \
            _Pragma("unroll")                                                   \
            for (int mi = 0; mi < 4; ++mi)                                      \
                _Pragma("unroll")                                               \
                for (int ni = 0; ni < 4; ++ni)                                  \
                    acc[mi][ni] = mfma16(af[mi], bfr[ni], acc[mi][ni]);         \
        }                                                                       \
    }

// QKV: X[4096][2048]bf16 @ {WqT|WkT|WvT}[N][2048] -> q/k/v [B,NH,T,D] bf16
__global__ __launch_bounds__(256)
void gemm_qkv_mfma(const __bf16* __restrict__ xb,
                   const __bf16* __restrict__ wqt,
                   const __bf16* __restrict__ wkt,
                   const __bf16* __restrict__ wvt,
                   __bf16* __restrict__ qbuf,
                   __bf16* __restrict__ kbuf,
                   __bf16* __restrict__ vbuf)
{
    const int n0 = blockIdx.x * 128;
    const int m0 = blockIdx.y * 128;
    const __bf16* Btp; __bf16* outb; int NH, nloc;
    if (n0 < 2048)      { Btp = wqt + (size_t)n0 * GK;          outb = qbuf; NH = 16; nloc = n0; }
    else if (n0 < 2560) { Btp = wkt + (size_t)(n0 - 2048) * GK; outb = kbuf; NH = 4;  nloc = n0 - 2048; }
    else                { Btp = wvt + (size_t)(n0 - 2560) * GK; outb = vbuf; NH = 4;  nloc = n0 - 2560; }
    const __bf16* Atp = xb + (size_t)m0 * GK;

    GEMM_MAIN(Atp, Btp)

    const int b  = m0 >> 11;
    const int t0 = m0 & (T_ - 1);
    const int h0 = nloc >> 7;
    __bf16* op = outb + (size_t)(b * NH + h0) * T_ * D_;
    #pragma unroll
    for (int mi = 0; mi < 4; ++mi)
        #pragma unroll
        for (int ni = 0; ni < 4; ++ni)
            #pragma unroll
            for (int rr = 0; rr < 4; ++rr) {
                const int row = t0 + wr * 64 + mi * 16 + bq * 4 + rr;
                const int col = wc * 64 + ni * 16 + a;
                op[(size_t)row * D_ + col] = (__bf16)acc[mi][ni][rr];
            }
}

// OUT: abuf[4096][2048]bf16 @ WoT[2048][2048] -> out fp32 [4096][2048]
__global__ __launch_bounds__(256)
void gemm_out_mfma(const __bf16* __restrict__ ab,
                   const __bf16* __restrict__ wot,
                   float* __restrict__ outp)
{
    const int n0 = blockIdx.x * 128;
    const int m0 = blockIdx.y * 128;
    const __bf16* Atp = ab + (size_t)m0 * GK;
    const __bf16* Btp = wot + (size_t)n0 * GK;

    GEMM_MAIN(Atp, Btp)

    #pragma unroll
    for (int mi = 0; mi < 4; ++mi)
        #pragma unroll
        for (int ni = 0; ni < 4; ++ni)
            #pragma unroll
            for (int rr = 0; rr < 4; ++rr) {
                const int row = m0 + wr * 64 + mi * 16 + bq * 4 + rr;
                const int col = n0 + wc * 64 + ni * 16 + a;
                outp[(size_t)row * C_ + col] = acc[mi][ni][rr];
            }
}

// ---------------------------------------------------------------------------
// RoPE in-place on bf16 [rows, D]
// ---------------------------------------------------------------------------
__global__ void rope_bf16(__bf16* __restrict__ buf)
{
    const int idx = blockIdx.x * blockDim.x + threadIdx.x;
    const int jj  = idx & 31;
    const int row = idx >> 5;
    const int t   = row & (T_ - 1);
    const int d   = jj * 2;

    const float LOG_THETA = 9.210340371976184f;
    const float f1 = (float)t * __expf(-(float)d       * (LOG_THETA / 64.0f));
    const float f2 = (float)t * __expf(-(float)(d + 1) * (LOG_THETA / 64.0f));
    float s1, c1, s2, c2;
    __sincosf(f1, &s1, &c1);
    __sincosf(f2, &s2, &c2);

    __bf16* p = buf + (size_t)row * D_ + d;
    const float x1a = (float)p[0],  x1b = (float)p[1];
    const float x2a = (float)p[64], x2b = (float)p[65];
    p[0]  = (__bf16)(x1a * c1 - x2a * s1);
    p[1]  = (__bf16)(x1b * c2 - x2b * s2);
    p[64] = (__bf16)(x2a * c1 + x1a * s1);
    p[65] = (__bf16)(x2b * c2 + x1b * s2);
}

// ---------------------------------------------------------------------------
// V transpose: vb [BH][T][D] -> vtb [BH][D][T]  (bf16)
// ---------------------------------------------------------------------------
__global__ __launch_bounds__(256)
void transpose_v(const __bf16* __restrict__ vb, __bf16* __restrict__ vtb)
{
    __shared__ __bf16 tl[32][33];
    const int tx = threadIdx.x;
    const int ty = threadIdx.y;
    const int t0 = blockIdx.x * 32;
    const int d0 = blockIdx.y * 32;
    const int bh = blockIdx.z;

    const __bf16* src = vb + ((size_t)bh * T_ + t0) * D_ + d0;
    #pragma unroll
    for (int i = 0; i < 4; ++i) {
        const int r = ty + i * 8;
        tl[r][tx] = src[(size_t)r * D_ + tx];
    }
    __syncthreads();
    __bf16* dst = vtb + ((size_t)bh * D_ + d0) * T_ + t0;
    #pragma unroll
    for (int i = 0; i < 4; ++i) {
        const int dl = ty + i * 8;
        dst[(size_t)dl * T_ + tx] = tl[tx][dl];
    }
}

// ---------------------------------------------------------------------------
// MFMA flash attention v3 (bf16 in, bf16 out). 512 thr = 8 waves, QBLK=128,
// KBLK=64, causal pairing (exact balance), async-stage (T14).
// V LDS d-stride padded to 36 elems: read bank = 18a mod 32, all-distinct
// (was 32 -> 8-way conflict, the round-5 8.9M). exp2-domain softmax.
// ---------------------------------------------------------------------------
#define KS_STRIDE 136   // K tile row stride (elems): 272 B
#define VS_STRIDE 36    // V tile d-stride (elems): 72 B
#define PS_STRIDE 76    // P tile row stride (elems): 152 B

__global__ __launch_bounds__(512)
void flash_attn_mfma(const __bf16* __restrict__ qb,
                     const __bf16* __restrict__ kb,
                     const __bf16* __restrict__ vtb,
                     __bf16* __restrict__ abuf)
{
    __shared__ __bf16 KsL[64 * KS_STRIDE];          // 17408 B
    __shared__ __bf16 VsL[2 * 128 * VS_STRIDE];     // 18432 B  [slice][d][36]
    __shared__ __bf16 PsL[8 * 16 * PS_STRIDE];      // 19456 B

    const int tid  = threadIdx.x;
    const int wave = tid >> 6;
    const int lane = tid & 63;
    const int a    = lane & 15;
    const int bq   = lane >> 4;

    const int pair = blockIdx.x;           // 0..7
    const int bh   = blockIdx.y;
    const int b    = bh >> 4;
    const int h    = bh & 15;
    const int kvh  = h >> 2;

    const __bf16* kg  = kb  + (size_t)(b * HKV_ + kvh) * T_ * D_;
    const __bf16* vtg = vtb + (size_t)(b * HKV_ + kvh) * D_ * T_;

    const float scale2 = 0.12750176129424902f;   // log2(e)/sqrt(128)

    for (int half = 0; half < 2; ++half) {
        const int qti = half == 0 ? (15 - pair) : pair;
        const int qt0 = qti * 128;
        const int ntiles = 2 * qti + 2;
        const int qrow_lo = qt0 + wave * 16;     // wave-uniform min q-row

        const __bf16* qg = qb + ((size_t)(b * H_ + h) * T_ + qrow_lo) * D_;
        bf16x8 qf[4];
        #pragma unroll
        for (int ks = 0; ks < 4; ++ks)
            qf[ks] = *(const bf16x8*)&qg[(size_t)a * D_ + ks * 32 + bq * 8];

        f32x4 oacc[8];
        #pragma unroll
        for (int dt = 0; dt < 8; ++dt) oacc[dt] = (f32x4){0.f, 0.f, 0.f, 0.f};
        float m_r[4] = {-INFINITY, -INFINITY, -INFINITY, -INFINITY};
        float l_r[4] = {0.f, 0.f, 0.f, 0.f};

        bf16x8 kpre[2], vpre[2];
        // prologue: stage tile 0
        #pragma unroll
        for (int it = 0; it < 2; ++it) {
            const int idx = it * 512 + tid;
            const int r = idx >> 4, c8 = (idx & 15) * 8;
            kpre[it] = *(const bf16x8*)&kg[(size_t)r * D_ + c8];
            const int bo = idx & 3, dd = (idx >> 2) & 127, ss2 = idx >> 9;
            vpre[it] = *(const bf16x8*)&vtg[(size_t)dd * T_ + ss2 * 32 + bo * 8];
        }
        __syncthreads();   // prior half's LDS reads complete
        #pragma unroll
        for (int it = 0; it < 2; ++it) {
            const int idx = it * 512 + tid;
            const int r = idx >> 4, c8 = (idx & 15) * 8;
            *(bf16x8*)&KsL[r * KS_STRIDE + c8] = kpre[it];
            const int bo = idx & 3, dd = (idx >> 2) & 127, ss2 = idx >> 9;
            *(bf16x8*)&VsL[(ss2 * 128 + dd) * VS_STRIDE + bo * 8] = vpre[it];
        }
        __syncthreads();

        for (int kt = 0; kt < ntiles; ++kt) {
            const int k0 = kt * 64;
            // issue next tile's global loads (latency hides under compute)
            if (kt + 1 < ntiles) {
                const int k0n = k0 + 64;
                #pragma unroll
                for (int it = 0; it < 2; ++it) {
                    const int idx = it * 512 + tid;
                    const int r = idx >> 4, c8 = (idx & 15) * 8;
                    kpre[it] = *(const bf16x8*)&kg[(size_t)(k0n + r) * D_ + c8];
                    const int bo = idx & 3, dd = (idx >> 2) & 127, ss2 = idx >> 9;
                    vpre[it] = *(const bf16x8*)&vtg[(size_t)dd * T_ + k0n + ss2 * 32 + bo * 8];
                }
            }

            // fully-masked tile for this wave? (wave-uniform) skip compute
            if (k0 <= qrow_lo + 15) {
                // S = Q K^T
                f32x4 sacc[4];
                #pragma unroll
                for (int nt = 0; nt < 4; ++nt) {
                    sacc[nt] = (f32x4){0.f, 0.f, 0.f, 0.f};
                    #pragma unroll
                    for (int ks = 0; ks < 4; ++ks) {
                        bf16x8 kf = *(const bf16x8*)&KsL[(nt * 16 + a) * KS_STRIDE + ks * 32 + bq * 8];
                        sacc[nt] = mfma16(qf[ks], kf, sacc[nt]);
                    }
                }

                // online softmax in exp2 domain (rows = bq*4+r, cols = k0+nt*16+a)
                float p[4][4];
                float mrow[4] = {-INFINITY, -INFINITY, -INFINITY, -INFINITY};
                const bool needmask = (k0 + 63 > qrow_lo);   // wave-uniform
                #pragma unroll
                for (int nt = 0; nt < 4; ++nt) {
                    const int kc = k0 + nt * 16 + a;
                    #pragma unroll
                    for (int r = 0; r < 4; ++r) {
                        float s = sacc[nt][r] * scale2;
                        if (needmask) {
                            const int qrow = qrow_lo + bq * 4 + r;
                            s = (kc <= qrow) ? s : -INFINITY;
                        }
                        p[nt][r] = s;
                        mrow[r] = fmaxf(mrow[r], s);
                    }
                }
                #pragma unroll
                for (int off = 1; off < 16; off <<= 1)
                    #pragma unroll
                    for (int r = 0; r < 4; ++r)
                        mrow[r] = fmaxf(mrow[r], __shfl_xor(mrow[r], off));

                float corr[4], psum[4];
                #pragma unroll
                for (int r = 0; r < 4; ++r) {
                    const float mnew = fmaxf(m_r[r], mrow[r]);
                    corr[r] = exp2f(m_r[r] - mnew);
                    m_r[r] = mnew;
                    psum[r] = 0.f;
                    #pragma unroll
                    for (int nt = 0; nt < 4; ++nt) {
                        const float pe = exp2f(p[nt][r] - mnew);
                        p[nt][r] = pe;
                        psum[r] += pe;
                    }
                }
                #pragma unroll
                for (int off = 1; off < 16; off <<= 1)
                    #pragma unroll
                    for (int r = 0; r < 4; ++r)
                        psum[r] += __shfl_xor(psum[r], off);
                #pragma unroll
                for (int r = 0; r < 4; ++r) l_r[r] = l_r[r] * corr[r] + psum[r];

                #pragma unroll
                for (int dt = 0; dt < 8; ++dt)
                    #pragma unroll
                    for (int r = 0; r < 4; ++r) oacc[dt][r] *= corr[r];

                // write P (bf16) to this wave's LDS region
                #pragma unroll
                for (int nt = 0; nt < 4; ++nt)
                    #pragma unroll
                    for (int r = 0; r < 4; ++r)
                        PsL[(wave * 16 + bq * 4 + r) * PS_STRIDE + nt * 16 + a] = (__bf16)p[nt][r];

                // O += P V
                bf16x8 pf[2];
                #pragma unroll
                for (int ss = 0; ss < 2; ++ss)
                    pf[ss] = *(const bf16x8*)&PsL[(wave * 16 + a) * PS_STRIDE + ss * 32 + bq * 8];
                #pragma unroll
                for (int dt = 0; dt < 8; ++dt) {
                    #pragma unroll
                    for (int ss = 0; ss < 2; ++ss) {
                        bf16x8 vf = *(const bf16x8*)&VsL[(ss * 128 + dt * 16 + a) * VS_STRIDE + bq * 8];
                        oacc[dt] = mfma16(pf[ss], vf, oacc[dt]);
                    }
                }
            }

            __syncthreads();   // all waves done reading K/V for this tile
            if (kt + 1 < ntiles) {
                #pragma unroll
                for (int it = 0; it < 2; ++it) {
                    const int idx = it * 512 + tid;
                    const int r = idx >> 4, c8 = (idx & 15) * 8;
                    *(bf16x8*)&KsL[r * KS_STRIDE + c8] = kpre[it];
                    const int bo = idx & 3, dd = (idx >> 2) & 127, ss2 = idx >> 9;
                    *(bf16x8*)&VsL[(ss2 * 128 + dd) * VS_STRIDE + bo * 8] = vpre[it];
                }
                __syncthreads();
            }
        }

        // epilogue
        float invl[4];
        #pragma unroll
        for (int r = 0; r < 4; ++r) invl[r] = 1.f / l_r[r];
        #pragma unroll
        for (int dt = 0; dt < 8; ++dt)
            #pragma unroll
            for (int r = 0; r < 4; ++r) {
                const int qrow = qrow_lo + bq * 4 + r;
                abuf[((size_t)(b * T_) + qrow) * (H_ * D_) + h * D_ + dt * 16 + a] =
                    (__bf16)(oacc[dt][r] * invl[r]);
            }
    }
}

// ---------------------------------------------------------------------------
extern "C" void kernel_launch(void* const* d_in, const int* in_sizes, int n_in,
                              void* d_out, int out_size, void* d_ws, size_t ws_size,
                              hipStream_t stream)
{
    (void)in_sizes; (void)n_in; (void)out_size; (void)ws_size;
    const float* x  = (const float*)d_in[0];
    const float* Wq = (const float*)d_in[1];
    const float* Wk = (const float*)d_in[2];
    const float* Wv = (const float*)d_in[3];
    const float* Wo = (const float*)d_in[4];
    float* out = (float*)d_out;

    __bf16* xb  = (__bf16*)d_ws;                      // 4096*2048
    __bf16* wqt = xb  + (size_t)4096 * 2048;          // 2048*2048
    __bf16* wkt = wqt + (size_t)2048 * 2048;          // 512*2048
    __bf16* wvt = wkt + (size_t)512 * 2048;           // 512*2048
    __bf16* wot = wvt + (size_t)512 * 2048;           // 2048*2048
    __bf16* qb  = wot + (size_t)2048 * 2048;          // B*H*T*D
    __bf16* kb  = qb  + (size_t)B_ * H_   * T_ * D_;
    __bf16* vb  = kb  + (size_t)B_ * HKV_ * T_ * D_;
    __bf16* vtb = vb  + (size_t)B_ * HKV_ * T_ * D_;
    __bf16* ab  = vtb + (size_t)B_ * HKV_ * T_ * D_;  // B*T*H*D bf16

    // 0) converts
    hipLaunchKernelGGL(conv_f32_bf16, dim3(4096), dim3(256), 0, stream,
                       x, xb, (int)((size_t)B_ * T_ * C_ / 8));
    hipLaunchKernelGGL(tconv, dim3(64, 64), dim3(32, 8), 0, stream, Wq, wqt, 2048);
    hipLaunchKernelGGL(tconv, dim3(64, 16), dim3(32, 8), 0, stream, Wk, wkt, 512);
    hipLaunchKernelGGL(tconv, dim3(64, 16), dim3(32, 8), 0, stream, Wv, wvt, 512);
    hipLaunchKernelGGL(tconv, dim3(64, 64), dim3(32, 8), 0, stream, Wo, wot, 2048);

    // 1) QKV projection (bf16 MFMA, global_load_lds staging)
    hipLaunchKernelGGL(gemm_qkv_mfma, dim3(24, 32), dim3(256), 0, stream,
                       xb, wqt, wkt, wvt, qb, kb, vb);

    // 2) RoPE on q and k
    hipLaunchKernelGGL(rope_bf16, dim3(B_ * H_ * T_ * 32 / 256), dim3(256), 0, stream, qb);
    hipLaunchKernelGGL(rope_bf16, dim3(B_ * HKV_ * T_ * 32 / 256), dim3(256), 0, stream, kb);

    // 3) V transpose
    hipLaunchKernelGGL(transpose_v, dim3(T_ / 32, D_ / 32, B_ * HKV_), dim3(32, 8), 0, stream,
                       vb, vtb);

    // 4) flash attention v3 -> ab (bf16)
    hipLaunchKernelGGL(flash_attn_mfma, dim3(8, B_ * H_), dim3(512), 0, stream,
                       qb, kb, vtb, ab);

    // 5) output projection (bf16 MFMA, fp32 out)
    hipLaunchKernelGGL(gemm_out_mfma, dim3(16, 32), dim3(256), 0, stream,
                       ab, wot, out);
}

// Round 7
// 355.702 us; speedup vs baseline: 1.0876x; 1.0876x over previous
//
#include <hip/hip_runtime.h>
#include <math.h>

#define B_ 2
#define T_ 2048
#define C_ 2048
#define H_ 16
#define HKV_ 4
#define D_ 128
#define G_ (H_ / HKV_)
#define GK 2048   // GEMM K dim (== C_)
#define NT9 32    // K-steps of 64

typedef float f32x4 __attribute__((ext_vector_type(4)));
typedef __bf16 bf16x8 __attribute__((ext_vector_type(8)));

static __device__ __forceinline__ f32x4 mfma16(bf16x8 a, bf16x8 b, f32x4 c) {
    return __builtin_amdgcn_mfma_f32_16x16x32_bf16(a, b, c, 0, 0, 0);
}

// async global->LDS, 16 B per lane; LDS base wave-uniform (HW adds lane*16),
// global address per-lane (enables source pre-swizzle).
static __device__ __forceinline__ void gload16(const __bf16* g, __bf16* l) {
    __builtin_amdgcn_global_load_lds(
        (const __attribute__((address_space(1))) unsigned int*)g,
        (__attribute__((address_space(3))) unsigned int*)l,
        16, 0, 0);
}

#define WRAP9(x) ((x) < 9 ? (x) : (x) - 9)

// ---------------------------------------------------------------------------
// 8-phase-style 256x256 GEMM, BK=64, 8 waves (2Mx4N), 9-slot half-tile LDS
// rotation (144 KiB). Counted vmcnt(2) per K-step (T4); XOR-swizzled LDS via
// pre-swizzled gload source + swizzled ds_read (T2, both-sides rule);
// setprio around MFMA clusters (T5). Raw s_barrier keeps loads in flight.
//
// Swizzle: physical col16-slot = logical_slot ^ (row&7). Stage: lane L covers
// row w*16+j*8+(L>>3), source col16 = (L&7)^(L>>3) -> linear LDS dest holds
// swizzled data. Read: elem_off = row*64 + ((ks*32+bq*8) ^ ((a&7)<<3)).
//
// Hazard proof (slot s reused for H(n) over H(n-9)): during K-step t we stage
// H(4t+5..4t+8); H(4t+5-9..4t+8-9) = halves of K-steps t-1 — all reads done
// before the K-step-t boundary barrier. Consumption: K-step t needs H(<=4t+3);
// issued-later = H(4t+4) only = 2 loads -> vmcnt(2). Final step: vmcnt(0).
// ---------------------------------------------------------------------------
#define STG(SRC, h, kk, slot) {                                                 \
    _Pragma("unroll")                                                           \
    for (int j_ = 0; j_ < 2; ++j_) {                                            \
        const int lr_ = (h) * 128 + wave * 16 + j_ * 8 + (lane >> 3);           \
        const int sc_ = ((lane & 7) ^ (lane >> 3)) << 3;                        \
        gload16(&(SRC)[(size_t)lr_ * GK + (kk) + sc_],                          \
                &sl[slot][(wave * 16 + j_ * 8) * 64]);                          \
    } }

#define GEMM8_MAIN(At, Bt)                                                      \
    __shared__ __bf16 sl[9][8192];                                              \
    const int tid = threadIdx.x;                                                \
    const int wave = tid >> 6, lane = tid & 63;                                 \
    const int a = lane & 15, bq = lane >> 4;                                    \
    const int wr = wave >> 2, wc = wave & 3;                                    \
    const int xl = (a & 7) << 3;                                                \
    const int brow = (wc & 1) * 64;                                             \
    f32x4 acc[8][4];                                                            \
    _Pragma("unroll")                                                           \
    for (int mi = 0; mi < 8; ++mi)                                              \
        _Pragma("unroll")                                                       \
        for (int ni = 0; ni < 4; ++ni) acc[mi][ni] = (f32x4){0.f,0.f,0.f,0.f};  \
    /* prologue: H0..H4 = A0(0),A1(0),B0(0),B1(0),A0(1) -> slots 0..4 */        \
    STG(At, 0, 0, 0) STG(At, 1, 0, 1) STG(Bt, 0, 0, 2) STG(Bt, 1, 0, 3)        \
    STG(At, 0, 64, 4)                                                           \
    int s0 = 0;                                                                 \
    _Pragma("unroll 1")                                                         \
    for (int t = 0; t < NT9; ++t) {                                             \
        if (t == NT9 - 1) { asm volatile("s_waitcnt vmcnt(0)" ::: "memory"); }  \
        else              { asm volatile("s_waitcnt vmcnt(2)" ::: "memory"); }  \
        __builtin_amdgcn_sched_barrier(0);                                      \
        __builtin_amdgcn_s_barrier();                                           \
        __builtin_amdgcn_sched_barrier(0);                                      \
        const int sA = WRAP9(s0 + wr);                                          \
        const int sB = WRAP9(s0 + 2 + (wc >> 1));                               \
        bf16x8 bf_[4][2];                                                       \
        _Pragma("unroll")                                                       \
        for (int ni = 0; ni < 4; ++ni)                                          \
            _Pragma("unroll")                                                   \
            for (int ks = 0; ks < 2; ++ks)                                      \
                bf_[ni][ks] = *(const bf16x8*)&sl[sB][(brow + ni*16 + a)*64 +   \
                                                      ((ks*32 + bq*8) ^ xl)];   \
        _Pragma("unroll")                                                       \
        for (int p = 0; p < 4; ++p) {                                           \
            bf16x8 af_[2][2];                                                   \
            _Pragma("unroll")                                                   \
            for (int m = 0; m < 2; ++m)                                         \
                _Pragma("unroll")                                               \
                for (int ks = 0; ks < 2; ++ks)                                  \
                    af_[m][ks] = *(const bf16x8*)&sl[sA][((p*2 + m)*16 + a)*64 +\
                                                         ((ks*32 + bq*8) ^ xl)];\
            if (p == 0 && t + 1 < NT9) STG(At, 1, (t+1)*64, WRAP9(s0 + 5))      \
            if (p == 1 && t + 1 < NT9) STG(Bt, 0, (t+1)*64, WRAP9(s0 + 6))      \
            if (p == 2 && t + 1 < NT9) STG(Bt, 1, (t+1)*64, WRAP9(s0 + 7))      \
            if (p == 3 && t + 2 < NT9) STG(At, 0, (t+2)*64, WRAP9(s0 + 8))      \
            __builtin_amdgcn_s_setprio(1);                                      \
            _Pragma("unroll")                                                   \
            for (int m = 0; m < 2; ++m)                                         \
                _Pragma("unroll")                                               \
                for (int ni = 0; ni < 4; ++ni) {                                \
                    acc[p*2+m][ni] = mfma16(af_[m][0], bf_[ni][0], acc[p*2+m][ni]); \
                    acc[p*2+m][ni] = mfma16(af_[m][1], bf_[ni][1], acc[p*2+m][ni]); \
                }                                                               \
            __builtin_amdgcn_s_setprio(0);                                      \
            if (p < 3) { __builtin_amdgcn_s_barrier(); }                        \
        }                                                                       \
        s0 += 4; if (s0 >= 9) s0 -= 9;                                          \
    }

// QKV: X[4096][2048]bf16 @ {WqT|WkT|WvT}[N][2048] -> q/k/v [B,NH,T,D] bf16
// grid 192 blocks (16m x 12n), XCD-clustered by m (A-panel locality).
__global__ __launch_bounds__(512, 1)
void gemm_qkv8(const __bf16* __restrict__ xb,
               const __bf16* __restrict__ wqt,
               const __bf16* __restrict__ wkt,
               const __bf16* __restrict__ wvt,
               __bf16* __restrict__ qbuf,
               __bf16* __restrict__ kbuf,
               __bf16* __restrict__ vbuf)
{
    const int bid = blockIdx.x;                 // 0..191
    const int swz = (bid & 7) * 24 + (bid >> 3);
    const int mti = swz / 12, nti = swz % 12;
    const int m0 = mti * 256, n0 = nti * 256;

    const __bf16* Btp; __bf16* outb; int NH, nloc;
    if (n0 < 2048)      { Btp = wqt + (size_t)n0 * GK;          outb = qbuf; NH = 16; nloc = n0; }
    else if (n0 < 2560) { Btp = wkt + (size_t)(n0 - 2048) * GK; outb = kbuf; NH = 4;  nloc = n0 - 2048; }
    else                { Btp = wvt + (size_t)(n0 - 2560) * GK; outb = vbuf; NH = 4;  nloc = n0 - 2560; }
    const __bf16* Atp = xb + (size_t)m0 * GK;

    GEMM8_MAIN(Atp, Btp)

    #pragma unroll
    for (int mi = 0; mi < 8; ++mi)
        #pragma unroll
        for (int ni = 0; ni < 4; ++ni) {
            const int col = nloc + wc * 64 + ni * 16 + a;
            const int head = col >> 7, d = col & 127;
            #pragma unroll
            for (int rr = 0; rr < 4; ++rr) {
                const int row = m0 + wr * 128 + mi * 16 + bq * 4 + rr;
                const int b = row >> 11, tt = row & (T_ - 1);
                outb[(((size_t)(b * NH + head)) * T_ + tt) * D_ + d] =
                    (__bf16)acc[mi][ni][rr];
            }
        }
}

// OUT: abuf[4096][2048]bf16 @ WoT[2048][2048] -> out fp32. 128 blocks (16m x 8n).
__global__ __launch_bounds__(512, 1)
void gemm_out8(const __bf16* __restrict__ ab,
               const __bf16* __restrict__ wot,
               float* __restrict__ outp)
{
    const int bid = blockIdx.x;                 // 0..127
    const int swz = (bid & 7) * 16 + (bid >> 3);
    const int mti = swz / 8, nti = swz % 8;
    const int m0 = mti * 256, n0 = nti * 256;
    const __bf16* Atp = ab + (size_t)m0 * GK;
    const __bf16* Btp = wot + (size_t)n0 * GK;

    GEMM8_MAIN(Atp, Btp)

    #pragma unroll
    for (int mi = 0; mi < 8; ++mi)
        #pragma unroll
        for (int ni = 0; ni < 4; ++ni) {
            const int col = n0 + wc * 64 + ni * 16 + a;
            #pragma unroll
            for (int rr = 0; rr < 4; ++rr) {
                const int row = m0 + wr * 128 + mi * 16 + bq * 4 + rr;
                outp[(size_t)row * C_ + col] = acc[mi][ni][rr];
            }
        }
}

// ---------------------------------------------------------------------------
// x fp32 -> bf16, 8 elems/thread
// ---------------------------------------------------------------------------
__global__ __launch_bounds__(256)
void conv_f32_bf16(const float* __restrict__ src, __bf16* __restrict__ dst, int n8)
{
    const int i = blockIdx.x * blockDim.x + threadIdx.x;
    if (i >= n8) return;
    const float4 a = *(const float4*)&src[(size_t)i * 8];
    const float4 b = *(const float4*)&src[(size_t)i * 8 + 4];
    bf16x8 o;
    o[0] = (__bf16)a.x; o[1] = (__bf16)a.y; o[2] = (__bf16)a.z; o[3] = (__bf16)a.w;
    o[4] = (__bf16)b.x; o[5] = (__bf16)b.y; o[6] = (__bf16)b.z; o[7] = (__bf16)b.w;
    *(bf16x8*)&dst[(size_t)i * 8] = o;
}

// ---------------------------------------------------------------------------
// W fp32 [K][N] -> bf16 [N][K]  (transpose + convert), 32x32 LDS tile
// ---------------------------------------------------------------------------
__global__ __launch_bounds__(256)
void tconv(const float* __restrict__ src, __bf16* __restrict__ dst, int N)
{
    __shared__ __bf16 tl[32][34];
    const int tx = threadIdx.x;   // 0..31
    const int ty = threadIdx.y;   // 0..7
    const int k0 = blockIdx.x * 32;
    const int n0 = blockIdx.y * 32;

    #pragma unroll
    for (int i = 0; i < 4; ++i) {
        const int r = ty + i * 8;
        tl[r][tx] = (__bf16)src[(size_t)(k0 + r) * N + n0 + tx];
    }
    __syncthreads();
    #pragma unroll
    for (int i = 0; i < 4; ++i) {
        const int r = ty + i * 8;
        dst[(size_t)(n0 + r) * GK + k0 + tx] = tl[tx][r];
    }
}

// ---------------------------------------------------------------------------
// RoPE in-place on bf16 [rows, D]; q and k buffers are contiguous -> 1 launch.
// ---------------------------------------------------------------------------
__global__ void rope_bf16(__bf16* __restrict__ buf)
{
    const int idx = blockIdx.x * blockDim.x + threadIdx.x;
    const int jj  = idx & 31;
    const int row = idx >> 5;
    const int t   = row & (T_ - 1);
    const int d   = jj * 2;

    const float LOG_THETA = 9.210340371976184f;
    const float f1 = (float)t * __expf(-(float)d       * (LOG_THETA / 64.0f));
    const float f2 = (float)t * __expf(-(float)(d + 1) * (LOG_THETA / 64.0f));
    float s1, c1, s2, c2;
    __sincosf(f1, &s1, &c1);
    __sincosf(f2, &s2, &c2);

    __bf16* p = buf + (size_t)row * D_ + d;
    const float x1a = (float)p[0],  x1b = (float)p[1];
    const float x2a = (float)p[64], x2b = (float)p[65];
    p[0]  = (__bf16)(x1a * c1 - x2a * s1);
    p[1]  = (__bf16)(x1b * c2 - x2b * s2);
    p[64] = (__bf16)(x2a * c1 + x1a * s1);
    p[65] = (__bf16)(x2b * c2 + x1b * s2);
}

// ---------------------------------------------------------------------------
// V transpose: vb [BH][T][D] -> vtb [BH][D][T]  (bf16)
// ---------------------------------------------------------------------------
__global__ __launch_bounds__(256)
void transpose_v(const __bf16* __restrict__ vb, __bf16* __restrict__ vtb)
{
    __shared__ __bf16 tl[32][33];
    const int tx = threadIdx.x;
    const int ty = threadIdx.y;
    const int t0 = blockIdx.x * 32;
    const int d0 = blockIdx.y * 32;
    const int bh = blockIdx.z;

    const __bf16* src = vb + ((size_t)bh * T_ + t0) * D_ + d0;
    #pragma unroll
    for (int i = 0; i < 4; ++i) {
        const int r = ty + i * 8;
        tl[r][tx] = src[(size_t)r * D_ + tx];
    }
    __syncthreads();
    __bf16* dst = vtb + ((size_t)bh * D_ + d0) * T_ + t0;
    #pragma unroll
    for (int i = 0; i < 4; ++i) {
        const int dl = ty + i * 8;
        dst[(size_t)dl * T_ + tx] = tl[tx][dl];
    }
}

// ---------------------------------------------------------------------------
// MFMA flash attention v3 (unchanged from round 6). 512 thr = 8 waves,
// QBLK=128, KBLK=64, causal pairing, async-stage, padded V, exp2 softmax.
// ---------------------------------------------------------------------------
#define KS_STRIDE 136
#define VS_STRIDE 36
#define PS_STRIDE 76

__global__ __launch_bounds__(512)
void flash_attn_mfma(const __bf16* __restrict__ qb,
                     const __bf16* __restrict__ kb,
                     const __bf16* __restrict__ vtb,
                     __bf16* __restrict__ abuf)
{
    __shared__ __bf16 KsL[64 * KS_STRIDE];
    __shared__ __bf16 VsL[2 * 128 * VS_STRIDE];
    __shared__ __bf16 PsL[8 * 16 * PS_STRIDE];

    const int tid  = threadIdx.x;
    const int wave = tid >> 6;
    const int lane = tid & 63;
    const int a    = lane & 15;
    const int bq   = lane >> 4;

    const int pair = blockIdx.x;
    const int bh   = blockIdx.y;
    const int b    = bh >> 4;
    const int h    = bh & 15;
    const int kvh  = h >> 2;

    const __bf16* kg  = kb  + (size_t)(b * HKV_ + kvh) * T_ * D_;
    const __bf16* vtg = vtb + (size_t)(b * HKV_ + kvh) * D_ * T_;

    const float scale2 = 0.12750176129424902f;   // log2(e)/sqrt(128)

    for (int half = 0; half < 2; ++half) {
        const int qti = half == 0 ? (15 - pair) : pair;
        const int qt0 = qti * 128;
        const int ntiles = 2 * qti + 2;
        const int qrow_lo = qt0 + wave * 16;

        const __bf16* qg = qb + ((size_t)(b * H_ + h) * T_ + qrow_lo) * D_;
        bf16x8 qf[4];
        #pragma unroll
        for (int ks = 0; ks < 4; ++ks)
            qf[ks] = *(const bf16x8*)&qg[(size_t)a * D_ + ks * 32 + bq * 8];

        f32x4 oacc[8];
        #pragma unroll
        for (int dt = 0; dt < 8; ++dt) oacc[dt] = (f32x4){0.f, 0.f, 0.f, 0.f};
        float m_r[4] = {-INFINITY, -INFINITY, -INFINITY, -INFINITY};
        float l_r[4] = {0.f, 0.f, 0.f, 0.f};

        bf16x8 kpre[2], vpre[2];
        #pragma unroll
        for (int it = 0; it < 2; ++it) {
            const int idx = it * 512 + tid;
            const int r = idx >> 4, c8 = (idx & 15) * 8;
            kpre[it] = *(const bf16x8*)&kg[(size_t)r * D_ + c8];
            const int bo = idx & 3, dd = (idx >> 2) & 127, ss2 = idx >> 9;
            vpre[it] = *(const bf16x8*)&vtg[(size_t)dd * T_ + ss2 * 32 + bo * 8];
        }
        __syncthreads();
        #pragma unroll
        for (int it = 0; it < 2; ++it) {
            const int idx = it * 512 + tid;
            const int r = idx >> 4, c8 = (idx & 15) * 8;
            *(bf16x8*)&KsL[r * KS_STRIDE + c8] = kpre[it];
            const int bo = idx & 3, dd = (idx >> 2) & 127, ss2 = idx >> 9;
            *(bf16x8*)&VsL[(ss2 * 128 + dd) * VS_STRIDE + bo * 8] = vpre[it];
        }
        __syncthreads();

        for (int kt = 0; kt < ntiles; ++kt) {
            const int k0 = kt * 64;
            if (kt + 1 < ntiles) {
                const int k0n = k0 + 64;
                #pragma unroll
                for (int it = 0; it < 2; ++it) {
                    const int idx = it * 512 + tid;
                    const int r = idx >> 4, c8 = (idx & 15) * 8;
                    kpre[it] = *(const bf16x8*)&kg[(size_t)(k0n + r) * D_ + c8];
                    const int bo = idx & 3, dd = (idx >> 2) & 127, ss2 = idx >> 9;
                    vpre[it] = *(const bf16x8*)&vtg[(size_t)dd * T_ + k0n + ss2 * 32 + bo * 8];
                }
            }

            if (k0 <= qrow_lo + 15) {
                f32x4 sacc[4];
                #pragma unroll
                for (int nt = 0; nt < 4; ++nt) {
                    sacc[nt] = (f32x4){0.f, 0.f, 0.f, 0.f};
                    #pragma unroll
                    for (int ks = 0; ks < 4; ++ks) {
                        bf16x8 kf = *(const bf16x8*)&KsL[(nt * 16 + a) * KS_STRIDE + ks * 32 + bq * 8];
                        sacc[nt] = mfma16(qf[ks], kf, sacc[nt]);
                    }
                }

                float p[4][4];
                float mrow[4] = {-INFINITY, -INFINITY, -INFINITY, -INFINITY};
                const bool needmask = (k0 + 63 > qrow_lo);
                #pragma unroll
                for (int nt = 0; nt < 4; ++nt) {
                    const int kc = k0 + nt * 16 + a;
                    #pragma unroll
                    for (int r = 0; r < 4; ++r) {
                        const int qrow = qrow_lo + bq * 4 + r;
                        float s = sacc[nt][r] * scale2;
                        if (needmask) s = (kc <= qrow) ? s : -INFINITY;
                        p[nt][r] = s;
                        mrow[r] = fmaxf(mrow[r], s);
                    }
                }
                #pragma unroll
                for (int off = 1; off < 16; off <<= 1)
                    #pragma unroll
                    for (int r = 0; r < 4; ++r)
                        mrow[r] = fmaxf(mrow[r], __shfl_xor(mrow[r], off));

                float corr[4], psum[4];
                #pragma unroll
                for (int r = 0; r < 4; ++r) {
                    const float mnew = fmaxf(m_r[r], mrow[r]);
                    corr[r] = exp2f(m_r[r] - mnew);
                    m_r[r] = mnew;
                    psum[r] = 0.f;
                    #pragma unroll
                    for (int nt = 0; nt < 4; ++nt) {
                        const float pe = exp2f(p[nt][r] - mnew);
                        p[nt][r] = pe;
                        psum[r] += pe;
                    }
                }
                #pragma unroll
                for (int off = 1; off < 16; off <<= 1)
                    #pragma unroll
                    for (int r = 0; r < 4; ++r)
                        psum[r] += __shfl_xor(psum[r], off);
                #pragma unroll
                for (int r = 0; r < 4; ++r) l_r[r] = l_r[r] * corr[r] + psum[r];

                #pragma unroll
                for (int dt = 0; dt < 8; ++dt)
                    #pragma unroll
                    for (int r = 0; r < 4; ++r) oacc[dt][r] *= corr[r];

                #pragma unroll
                for (int nt = 0; nt < 4; ++nt)
                    #pragma unroll
                    for (int r = 0; r < 4; ++r)
                        PsL[(wave * 16 + bq * 4 + r) * PS_STRIDE + nt * 16 + a] = (__bf16)p[nt][r];

                bf16x8 pf[2];
                #pragma unroll
                for (int ss = 0; ss < 2; ++ss)
                    pf[ss] = *(const bf16x8*)&PsL[(wave * 16 + a) * PS_STRIDE + ss * 32 + bq * 8];
                #pragma unroll
                for (int dt = 0; dt < 8; ++dt) {
                    #pragma unroll
                    for (int ss = 0; ss < 2; ++ss) {
                        bf16x8 vf = *(const bf16x8*)&VsL[(ss * 128 + dt * 16 + a) * VS_STRIDE + bq * 8];
                        oacc[dt] = mfma16(pf[ss], vf, oacc[dt]);
                    }
                }
            }

            __syncthreads();
            if (kt + 1 < ntiles) {
                #pragma unroll
                for (int it = 0; it < 2; ++it) {
                    const int idx = it * 512 + tid;
                    const int r = idx >> 4, c8 = (idx & 15) * 8;
                    *(bf16x8*)&KsL[r * KS_STRIDE + c8] = kpre[it];
                    const int bo = idx & 3, dd = (idx >> 2) & 127, ss2 = idx >> 9;
                    *(bf16x8*)&VsL[(ss2 * 128 + dd) * VS_STRIDE + bo * 8] = vpre[it];
                }
                __syncthreads();
            }
        }

        float invl[4];
        #pragma unroll
        for (int r = 0; r < 4; ++r) invl[r] = 1.f / l_r[r];
        #pragma unroll
        for (int dt = 0; dt < 8; ++dt)
            #pragma unroll
            for (int r = 0; r < 4; ++r) {
                const int qrow = qrow_lo + bq * 4 + r;
                abuf[((size_t)(b * T_) + qrow) * (H_ * D_) + h * D_ + dt * 16 + a] =
                    (__bf16)(oacc[dt][r] * invl[r]);
            }
    }
}

// ---------------------------------------------------------------------------
extern "C" void kernel_launch(void* const* d_in, const int* in_sizes, int n_in,
                              void* d_out, int out_size, void* d_ws, size_t ws_size,
                              hipStream_t stream)
{
    (void)in_sizes; (void)n_in; (void)out_size; (void)ws_size;
    const float* x  = (const float*)d_in[0];
    const float* Wq = (const float*)d_in[1];
    const float* Wk = (const float*)d_in[2];
    const float* Wv = (const float*)d_in[3];
    const float* Wo = (const float*)d_in[4];
    float* out = (float*)d_out;

    __bf16* xb  = (__bf16*)d_ws;                      // 4096*2048
    __bf16* wqt = xb  + (size_t)4096 * 2048;          // 2048*2048
    __bf16* wkt = wqt + (size_t)2048 * 2048;          // 512*2048
    __bf16* wvt = wkt + (size_t)512 * 2048;           // 512*2048
    __bf16* wot = wvt + (size_t)512 * 2048;           // 2048*2048
    __bf16* qb  = wot + (size_t)2048 * 2048;          // B*H*T*D
    __bf16* kb  = qb  + (size_t)B_ * H_   * T_ * D_;  // contiguous after qb
    __bf16* vb  = kb  + (size_t)B_ * HKV_ * T_ * D_;
    __bf16* vtb = vb  + (size_t)B_ * HKV_ * T_ * D_;
    __bf16* ab  = vtb + (size_t)B_ * HKV_ * T_ * D_;  // B*T*H*D bf16

    // 0) converts
    hipLaunchKernelGGL(conv_f32_bf16, dim3(4096), dim3(256), 0, stream,
                       x, xb, (int)((size_t)B_ * T_ * C_ / 8));
    hipLaunchKernelGGL(tconv, dim3(64, 64), dim3(32, 8), 0, stream, Wq, wqt, 2048);
    hipLaunchKernelGGL(tconv, dim3(64, 16), dim3(32, 8), 0, stream, Wk, wkt, 512);
    hipLaunchKernelGGL(tconv, dim3(64, 16), dim3(32, 8), 0, stream, Wv, wvt, 512);
    hipLaunchKernelGGL(tconv, dim3(64, 64), dim3(32, 8), 0, stream, Wo, wot, 2048);

    // 1) QKV projection (8-phase 256^2 MFMA)
    hipLaunchKernelGGL(gemm_qkv8, dim3(192), dim3(512), 0, stream,
                       xb, wqt, wkt, wvt, qb, kb, vb);

    // 2) RoPE on q and k (contiguous -> one launch)
    hipLaunchKernelGGL(rope_bf16, dim3(B_ * (H_ + HKV_) * T_ * 32 / 256), dim3(256),
                       0, stream, qb);

    // 3) V transpose
    hipLaunchKernelGGL(transpose_v, dim3(T_ / 32, D_ / 32, B_ * HKV_), dim3(32, 8), 0, stream,
                       vb, vtb);

    // 4) flash attention -> ab (bf16)
    hipLaunchKernelGGL(flash_attn_mfma, dim3(8, B_ * H_), dim3(512), 0, stream,
                       qb, kb, vtb, ab);

    // 5) output projection (8-phase 256^2 MFMA, fp32 out)
    hipLaunchKernelGGL(gemm_out8, dim3(128), dim3(512), 0, stream,
                       ab, wot, out);
}

// Round 9
// 344.065 us; speedup vs baseline: 1.1244x; 1.0338x over previous
//
#include <hip/hip_runtime.h>
#include <math.h>

#define B_ 2
#define T_ 2048
#define C_ 2048
#define H_ 16
#define HKV_ 4
#define D_ 128
#define G_ (H_ / HKV_)
#define GK 2048   // GEMM K dim (== C_)
#define NT9 32    // K-steps of 64

typedef float f32x4 __attribute__((ext_vector_type(4)));
typedef __bf16 bf16x8 __attribute__((ext_vector_type(8)));

static __device__ __forceinline__ f32x4 mfma16(bf16x8 a, bf16x8 b, f32x4 c) {
    return __builtin_amdgcn_mfma_f32_16x16x32_bf16(a, b, c, 0, 0, 0);
}

// async global->LDS, 16 B per lane; LDS base wave-uniform (HW adds lane*16),
// global address per-lane (enables source pre-swizzle).
static __device__ __forceinline__ void gload16(const __bf16* g, __bf16* l) {
    __builtin_amdgcn_global_load_lds(
        (const __attribute__((address_space(1))) unsigned int*)g,
        (__attribute__((address_space(3))) unsigned int*)l,
        16, 0, 0);
}

#define WRAP9(x) ((x) < 9 ? (x) : (x) - 9)

// ---------------------------------------------------------------------------
// 8-phase-style 256x256 GEMM (unchanged), BK=64, 8 waves, 9-slot half-tile
// rotation, counted vmcnt, XOR swizzle, setprio.
// ---------------------------------------------------------------------------
#define STG(SRC, h, kk, slot) {                                                 \
    _Pragma("unroll")                                                           \
    for (int j_ = 0; j_ < 2; ++j_) {                                            \
        const int lr_ = (h) * 128 + wave * 16 + j_ * 8 + (lane >> 3);           \
        const int sc_ = ((lane & 7) ^ (lane >> 3)) << 3;                        \
        gload16(&(SRC)[(size_t)lr_ * GK + (kk) + sc_],                          \
                &sl[slot][(wave * 16 + j_ * 8) * 64]);                          \
    } }

#define GEMM8_MAIN(At, Bt)                                                      \
    __shared__ __bf16 sl[9][8192];                                              \
    const int tid = threadIdx.x;                                                \
    const int wave = tid >> 6, lane = tid & 63;                                 \
    const int a = lane & 15, bq = lane >> 4;                                    \
    const int wr = wave >> 2, wc = wave & 3;                                    \
    const int xl = (a & 7) << 3;                                                \
    const int brow = (wc & 1) * 64;                                             \
    f32x4 acc[8][4];                                                            \
    _Pragma("unroll")                                                           \
    for (int mi = 0; mi < 8; ++mi)                                              \
        _Pragma("unroll")                                                       \
        for (int ni = 0; ni < 4; ++ni) acc[mi][ni] = (f32x4){0.f,0.f,0.f,0.f};  \
    STG(At, 0, 0, 0) STG(At, 1, 0, 1) STG(Bt, 0, 0, 2) STG(Bt, 1, 0, 3)        \
    STG(At, 0, 64, 4)                                                           \
    int s0 = 0;                                                                 \
    _Pragma("unroll 1")                                                         \
    for (int t = 0; t < NT9; ++t) {                                             \
        if (t == NT9 - 1) { asm volatile("s_waitcnt vmcnt(0)" ::: "memory"); }  \
        else              { asm volatile("s_waitcnt vmcnt(2)" ::: "memory"); }  \
        __builtin_amdgcn_sched_barrier(0);                                      \
        __builtin_amdgcn_s_barrier();                                           \
        __builtin_amdgcn_sched_barrier(0);                                      \
        const int sA = WRAP9(s0 + wr);                                          \
        const int sB = WRAP9(s0 + 2 + (wc >> 1));                               \
        bf16x8 bf_[4][2];                                                       \
        _Pragma("unroll")                                                       \
        for (int ni = 0; ni < 4; ++ni)                                          \
            _Pragma("unroll")                                                   \
            for (int ks = 0; ks < 2; ++ks)                                      \
                bf_[ni][ks] = *(const bf16x8*)&sl[sB][(brow + ni*16 + a)*64 +   \
                                                      ((ks*32 + bq*8) ^ xl)];   \
        _Pragma("unroll")                                                       \
        for (int p = 0; p < 4; ++p) {                                           \
            bf16x8 af_[2][2];                                                   \
            _Pragma("unroll")                                                   \
            for (int m = 0; m < 2; ++m)                                         \
                _Pragma("unroll")                                               \
                for (int ks = 0; ks < 2; ++ks)                                  \
                    af_[m][ks] = *(const bf16x8*)&sl[sA][((p*2 + m)*16 + a)*64 +\
                                                         ((ks*32 + bq*8) ^ xl)];\
            if (p == 0 && t + 1 < NT9) STG(At, 1, (t+1)*64, WRAP9(s0 + 5))      \
            if (p == 1 && t + 1 < NT9) STG(Bt, 0, (t+1)*64, WRAP9(s0 + 6))      \
            if (p == 2 && t + 1 < NT9) STG(Bt, 1, (t+1)*64, WRAP9(s0 + 7))      \
            if (p == 3 && t + 2 < NT9) STG(At, 0, (t+2)*64, WRAP9(s0 + 8))      \
            __builtin_amdgcn_s_setprio(1);                                      \
            _Pragma("unroll")                                                   \
            for (int m = 0; m < 2; ++m)                                         \
                _Pragma("unroll")                                               \
                for (int ni = 0; ni < 4; ++ni) {                                \
                    acc[p*2+m][ni] = mfma16(af_[m][0], bf_[ni][0], acc[p*2+m][ni]); \
                    acc[p*2+m][ni] = mfma16(af_[m][1], bf_[ni][1], acc[p*2+m][ni]); \
                }                                                               \
            __builtin_amdgcn_s_setprio(0);                                      \
            if (p < 3) { __builtin_amdgcn_s_barrier(); }                        \
        }                                                                       \
        s0 += 4; if (s0 >= 9) s0 -= 9;                                          \
    }

__global__ __launch_bounds__(512, 1)
void gemm_qkv8(const __bf16* __restrict__ xb,
               const __bf16* __restrict__ wqt,
               const __bf16* __restrict__ wkt,
               const __bf16* __restrict__ wvt,
               __bf16* __restrict__ qbuf,
               __bf16* __restrict__ kbuf,
               __bf16* __restrict__ vbuf)
{
    const int bid = blockIdx.x;                 // 0..191
    const int swz = (bid & 7) * 24 + (bid >> 3);
    const int mti = swz / 12, nti = swz % 12;
    const int m0 = mti * 256, n0 = nti * 256;

    const __bf16* Btp; __bf16* outb; int NH, nloc;
    if (n0 < 2048)      { Btp = wqt + (size_t)n0 * GK;          outb = qbuf; NH = 16; nloc = n0; }
    else if (n0 < 2560) { Btp = wkt + (size_t)(n0 - 2048) * GK; outb = kbuf; NH = 4;  nloc = n0 - 2048; }
    else                { Btp = wvt + (size_t)(n0 - 2560) * GK; outb = vbuf; NH = 4;  nloc = n0 - 2560; }
    const __bf16* Atp = xb + (size_t)m0 * GK;

    GEMM8_MAIN(Atp, Btp)

    #pragma unroll
    for (int mi = 0; mi < 8; ++mi)
        #pragma unroll
        for (int ni = 0; ni < 4; ++ni) {
            const int col = nloc + wc * 64 + ni * 16 + a;
            const int head = col >> 7, d = col & 127;
            #pragma unroll
            for (int rr = 0; rr < 4; ++rr) {
                const int row = m0 + wr * 128 + mi * 16 + bq * 4 + rr;
                const int b = row >> 11, tt = row & (T_ - 1);
                outb[(((size_t)(b * NH + head)) * T_ + tt) * D_ + d] =
                    (__bf16)acc[mi][ni][rr];
            }
        }
}

__global__ __launch_bounds__(512, 1)
void gemm_out8(const __bf16* __restrict__ ab,
               const __bf16* __restrict__ wot,
               float* __restrict__ outp)
{
    const int bid = blockIdx.x;                 // 0..127
    const int swz = (bid & 7) * 16 + (bid >> 3);
    const int mti = swz / 8, nti = swz % 8;
    const int m0 = mti * 256, n0 = nti * 256;
    const __bf16* Atp = ab + (size_t)m0 * GK;
    const __bf16* Btp = wot + (size_t)n0 * GK;

    GEMM8_MAIN(Atp, Btp)

    #pragma unroll
    for (int mi = 0; mi < 8; ++mi)
        #pragma unroll
        for (int ni = 0; ni < 4; ++ni) {
            const int col = n0 + wc * 64 + ni * 16 + a;
            #pragma unroll
            for (int rr = 0; rr < 4; ++rr) {
                const int row = m0 + wr * 128 + mi * 16 + bq * 4 + rr;
                outp[(size_t)row * C_ + col] = acc[mi][ni][rr];
            }
        }
}

// ---------------------------------------------------------------------------
__global__ __launch_bounds__(256)
void conv_f32_bf16(const float* __restrict__ src, __bf16* __restrict__ dst, int n8)
{
    const int i = blockIdx.x * blockDim.x + threadIdx.x;
    if (i >= n8) return;
    const float4 a = *(const float4*)&src[(size_t)i * 8];
    const float4 b = *(const float4*)&src[(size_t)i * 8 + 4];
    bf16x8 o;
    o[0] = (__bf16)a.x; o[1] = (__bf16)a.y; o[2] = (__bf16)a.z; o[3] = (__bf16)a.w;
    o[4] = (__bf16)b.x; o[5] = (__bf16)b.y; o[6] = (__bf16)b.z; o[7] = (__bf16)b.w;
    *(bf16x8*)&dst[(size_t)i * 8] = o;
}

__global__ __launch_bounds__(256)
void tconv(const float* __restrict__ src, __bf16* __restrict__ dst, int N)
{
    __shared__ __bf16 tl[32][34];
    const int tx = threadIdx.x;
    const int ty = threadIdx.y;
    const int k0 = blockIdx.x * 32;
    const int n0 = blockIdx.y * 32;

    #pragma unroll
    for (int i = 0; i < 4; ++i) {
        const int r = ty + i * 8;
        tl[r][tx] = (__bf16)src[(size_t)(k0 + r) * N + n0 + tx];
    }
    __syncthreads();
    #pragma unroll
    for (int i = 0; i < 4; ++i) {
        const int r = ty + i * 8;
        dst[(size_t)(n0 + r) * GK + k0 + tx] = tl[tx][r];
    }
}

__global__ void rope_bf16(__bf16* __restrict__ buf)
{
    const int idx = blockIdx.x * blockDim.x + threadIdx.x;
    const int jj  = idx & 31;
    const int row = idx >> 5;
    const int t   = row & (T_ - 1);
    const int d   = jj * 2;

    const float LOG_THETA = 9.210340371976184f;
    const float f1 = (float)t * __expf(-(float)d       * (LOG_THETA / 64.0f));
    const float f2 = (float)t * __expf(-(float)(d + 1) * (LOG_THETA / 64.0f));
    float s1, c1, s2, c2;
    __sincosf(f1, &s1, &c1);
    __sincosf(f2, &s2, &c2);

    __bf16* p = buf + (size_t)row * D_ + d;
    const float x1a = (float)p[0],  x1b = (float)p[1];
    const float x2a = (float)p[64], x2b = (float)p[65];
    p[0]  = (__bf16)(x1a * c1 - x2a * s1);
    p[1]  = (__bf16)(x1b * c2 - x2b * s2);
    p[64] = (__bf16)(x2a * c1 + x1a * s1);
    p[65] = (__bf16)(x2b * c2 + x1b * s2);
}

__global__ __launch_bounds__(256)
void transpose_v(const __bf16* __restrict__ vb, __bf16* __restrict__ vtb)
{
    __shared__ __bf16 tl[32][33];
    const int tx = threadIdx.x;
    const int ty = threadIdx.y;
    const int t0 = blockIdx.x * 32;
    const int d0 = blockIdx.y * 32;
    const int bh = blockIdx.z;

    const __bf16* src = vb + ((size_t)bh * T_ + t0) * D_ + d0;
    #pragma unroll
    for (int i = 0; i < 4; ++i) {
        const int r = ty + i * 8;
        tl[r][tx] = src[(size_t)r * D_ + tx];
    }
    __syncthreads();
    __bf16* dst = vtb + ((size_t)bh * D_ + d0) * T_ + t0;
    #pragma unroll
    for (int i = 0; i < 4; ++i) {
        const int dl = ty + i * 8;
        dst[(size_t)dl * T_ + tx] = tl[tx][dl];
    }
}

// ---------------------------------------------------------------------------
// MFMA flash attention v4. 512 thr = 8 waves, QBLK=128, KBLK=128, causal
// pairing. Per-tile fixed costs (barriers, shfl reduces, rescale) amortized
// over 128 cols. Diagonal-tile wave-uniform skip; T13 defer-max rescale skip.
// Async reg-staged K/V (4+4 loads/thread/tile).
// ---------------------------------------------------------------------------
#define KS_STRIDE 136   // 272 B row stride: bank 4a mod 32 -> 2-way (free)
#define VS_STRIDE 36    // 72 B d-stride: bank 18a mod 32 -> distinct
#define PS_STRIDE 136   // b128-aligned rows; read bank 4a mod 32 -> 2-way

__global__ __launch_bounds__(512)
void flash_attn_mfma(const __bf16* __restrict__ qb,
                     const __bf16* __restrict__ kb,
                     const __bf16* __restrict__ vtb,
                     __bf16* __restrict__ abuf)
{
    __shared__ __bf16 KsL[128 * KS_STRIDE];        // 34816 B
    __shared__ __bf16 VsL[4 * 128 * VS_STRIDE];    // 36864 B  [slice][d][36]
    __shared__ __bf16 PsL[8 * 16 * PS_STRIDE];     // 34816 B

    const int tid  = threadIdx.x;
    const int wave = tid >> 6;
    const int lane = tid & 63;
    const int a    = lane & 15;
    const int bq   = lane >> 4;

    const int pair = blockIdx.x;           // 0..7
    const int bh   = blockIdx.y;
    const int b    = bh >> 4;
    const int h    = bh & 15;
    const int kvh  = h >> 2;

    const __bf16* kg  = kb  + (size_t)(b * HKV_ + kvh) * T_ * D_;
    const __bf16* vtg = vtb + (size_t)(b * HKV_ + kvh) * D_ * T_;

    const float scale2 = 0.12750176129424902f;   // log2(e)/sqrt(128)

    for (int half = 0; half < 2; ++half) {
        const int qti = half == 0 ? (15 - pair) : pair;
        const int qt0 = qti * 128;
        const int ntiles = qti + 1;            // K-tiles of 128
        const int qrow_lo = qt0 + wave * 16;

        const __bf16* qg = qb + ((size_t)(b * H_ + h) * T_ + qrow_lo) * D_;
        bf16x8 qf[4];
        #pragma unroll
        for (int ks = 0; ks < 4; ++ks)
            qf[ks] = *(const bf16x8*)&qg[(size_t)a * D_ + ks * 32 + bq * 8];

        f32x4 oacc[8];
        #pragma unroll
        for (int dt = 0; dt < 8; ++dt) oacc[dt] = (f32x4){0.f, 0.f, 0.f, 0.f};
        float m_r[4] = {-INFINITY, -INFINITY, -INFINITY, -INFINITY};
        float l_r[4] = {0.f, 0.f, 0.f, 0.f};

        bf16x8 kpre[4], vpre[4];
        // prologue: stage K/V tile 0 (128x128 each)
        #pragma unroll
        for (int it = 0; it < 4; ++it) {
            const int idx = it * 512 + tid;
            const int r = idx >> 4, c8 = (idx & 15) * 8;
            kpre[it] = *(const bf16x8*)&kg[(size_t)r * D_ + c8];
            const int bo = idx & 3, dd = (idx >> 2) & 127, ss2 = idx >> 9;
            vpre[it] = *(const bf16x8*)&vtg[(size_t)dd * T_ + ss2 * 32 + bo * 8];
        }
        __syncthreads();   // prior half's LDS reads complete
        #pragma unroll
        for (int it = 0; it < 4; ++it) {
            const int idx = it * 512 + tid;
            const int r = idx >> 4, c8 = (idx & 15) * 8;
            *(bf16x8*)&KsL[r * KS_STRIDE + c8] = kpre[it];
            const int bo = idx & 3, dd = (idx >> 2) & 127, ss2 = idx >> 9;
            *(bf16x8*)&VsL[(ss2 * 128 + dd) * VS_STRIDE + bo * 8] = vpre[it];
        }
        __syncthreads();

        for (int kt = 0; kt < ntiles; ++kt) {
            const int k0 = kt * 128;
            // issue next tile's global loads (hide under compute)
            if (kt + 1 < ntiles) {
                const int k0n = k0 + 128;
                #pragma unroll
                for (int it = 0; it < 4; ++it) {
                    const int idx = it * 512 + tid;
                    const int r = idx >> 4, c8 = (idx & 15) * 8;
                    kpre[it] = *(const bf16x8*)&kg[(size_t)(k0n + r) * D_ + c8];
                    const int bo = idx & 3, dd = (idx >> 2) & 127, ss2 = idx >> 9;
                    vpre[it] = *(const bf16x8*)&vtg[(size_t)dd * T_ + k0n + ss2 * 32 + bo * 8];
                }
            }

            const bool diag = (kt == ntiles - 1);          // k0 == qt0
            const int nlim  = diag ? wave : 7;             // wave-uniform
            const int sslim = diag ? (wave >> 1) : 3;

            // S = Q K^T over live column blocks
            float p[8][4];
            float mrow[4] = {-INFINITY, -INFINITY, -INFINITY, -INFINITY};
            #pragma unroll
            for (int nt = 0; nt < 8; ++nt) {
                if (nt <= nlim) {
                    f32x4 sacc = (f32x4){0.f, 0.f, 0.f, 0.f};
                    #pragma unroll
                    for (int ks = 0; ks < 4; ++ks) {
                        bf16x8 kf = *(const bf16x8*)&KsL[(nt * 16 + a) * KS_STRIDE + ks * 32 + bq * 8];
                        sacc = mfma16(qf[ks], kf, sacc);
                    }
                    const int kc = k0 + nt * 16 + a;
                    #pragma unroll
                    for (int r = 0; r < 4; ++r) {
                        float s = sacc[r] * scale2;
                        if (diag) {
                            const int qrow = qrow_lo + bq * 4 + r;
                            s = (kc <= qrow) ? s : -INFINITY;
                        }
                        p[nt][r] = s;
                        mrow[r] = fmaxf(mrow[r], s);
                    }
                } else {
                    #pragma unroll
                    for (int r = 0; r < 4; ++r) p[nt][r] = -INFINITY;
                }
            }
            #pragma unroll
            for (int off = 1; off < 16; off <<= 1)
                #pragma unroll
                for (int r = 0; r < 4; ++r)
                    mrow[r] = fmaxf(mrow[r], __shfl_xor(mrow[r], off));

            // defer-max: skip rescale when max growth <= 11 log2-units (~e^8)
            bool dfr = true;
            #pragma unroll
            for (int r = 0; r < 4; ++r) dfr = dfr && (mrow[r] <= m_r[r] + 11.0f);
            dfr = __all(dfr);
            float mnew[4];
            #pragma unroll
            for (int r = 0; r < 4; ++r)
                mnew[r] = dfr ? m_r[r] : fmaxf(m_r[r], mrow[r]);

            // exp + P write (zeros for dead blocks; PsL fully rewritten each tile)
            float psum[4] = {0.f, 0.f, 0.f, 0.f};
            #pragma unroll
            for (int nt = 0; nt < 8; ++nt) {
                if (nt <= nlim) {
                    #pragma unroll
                    for (int r = 0; r < 4; ++r) {
                        const float pe = exp2f(p[nt][r] - mnew[r]);
                        psum[r] += pe;
                        PsL[(wave * 16 + bq * 4 + r) * PS_STRIDE + nt * 16 + a] = (__bf16)pe;
                    }
                } else {
                    #pragma unroll
                    for (int r = 0; r < 4; ++r)
                        PsL[(wave * 16 + bq * 4 + r) * PS_STRIDE + nt * 16 + a] = (__bf16)0.f;
                }
            }
            #pragma unroll
            for (int off = 1; off < 16; off <<= 1)
                #pragma unroll
                for (int r = 0; r < 4; ++r)
                    psum[r] += __shfl_xor(psum[r], off);

            if (!dfr) {
                float corr[4];
                #pragma unroll
                for (int r = 0; r < 4; ++r) {
                    corr[r] = exp2f(m_r[r] - mnew[r]);
                    m_r[r] = mnew[r];
                    l_r[r] = l_r[r] * corr[r] + psum[r];
                }
                #pragma unroll
                for (int dt = 0; dt < 8; ++dt)
                    #pragma unroll
                    for (int r = 0; r < 4; ++r) oacc[dt][r] *= corr[r];
            } else {
                #pragma unroll
                for (int r = 0; r < 4; ++r) l_r[r] += psum[r];
            }

            // O += P V over live k-slices
            #pragma unroll
            for (int ss = 0; ss < 4; ++ss) {
                if (ss <= sslim) {
                    const bf16x8 pf =
                        *(const bf16x8*)&PsL[(wave * 16 + a) * PS_STRIDE + ss * 32 + bq * 8];
                    #pragma unroll
                    for (int dt = 0; dt < 8; ++dt) {
                        bf16x8 vf = *(const bf16x8*)&VsL[(ss * 128 + dt * 16 + a) * VS_STRIDE + bq * 8];
                        oacc[dt] = mfma16(pf, vf, oacc[dt]);
                    }
                }
            }

            __syncthreads();   // all waves done reading K/V
            if (kt + 1 < ntiles) {
                #pragma unroll
                for (int it = 0; it < 4; ++it) {
                    const int idx = it * 512 + tid;
                    const int r = idx >> 4, c8 = (idx & 15) * 8;
                    *(bf16x8*)&KsL[r * KS_STRIDE + c8] = kpre[it];
                    const int bo = idx & 3, dd = (idx >> 2) & 127, ss2 = idx >> 9;
                    *(bf16x8*)&VsL[(ss2 * 128 + dd) * VS_STRIDE + bo * 8] = vpre[it];
                }
                __syncthreads();
            }
        }

        // epilogue
        float invl[4];
        #pragma unroll
        for (int r = 0; r < 4; ++r) invl[r] = 1.f / l_r[r];
        #pragma unroll
        for (int dt = 0; dt < 8; ++dt)
            #pragma unroll
            for (int r = 0; r < 4; ++r) {
                const int qrow = qrow_lo + bq * 4 + r;
                abuf[((size_t)(b * T_) + qrow) * (H_ * D_) + h * D_ + dt * 16 + a] =
                    (__bf16)(oacc[dt][r] * invl[r]);
            }
    }
}

// ---------------------------------------------------------------------------
extern "C" void kernel_launch(void* const* d_in, const int* in_sizes, int n_in,
                              void* d_out, int out_size, void* d_ws, size_t ws_size,
                              hipStream_t stream)
{
    (void)in_sizes; (void)n_in; (void)out_size; (void)ws_size;
    const float* x  = (const float*)d_in[0];
    const float* Wq = (const float*)d_in[1];
    const float* Wk = (const float*)d_in[2];
    const float* Wv = (const float*)d_in[3];
    const float* Wo = (const float*)d_in[4];
    float* out = (float*)d_out;

    __bf16* xb  = (__bf16*)d_ws;                      // 4096*2048
    __bf16* wqt = xb  + (size_t)4096 * 2048;          // 2048*2048
    __bf16* wkt = wqt + (size_t)2048 * 2048;          // 512*2048
    __bf16* wvt = wkt + (size_t)512 * 2048;           // 512*2048
    __bf16* wot = wvt + (size_t)512 * 2048;           // 2048*2048
    __bf16* qb  = wot + (size_t)2048 * 2048;          // B*H*T*D
    __bf16* kb  = qb  + (size_t)B_ * H_   * T_ * D_;  // contiguous after qb
    __bf16* vb  = kb  + (size_t)B_ * HKV_ * T_ * D_;
    __bf16* vtb = vb  + (size_t)B_ * HKV_ * T_ * D_;
    __bf16* ab  = vtb + (size_t)B_ * HKV_ * T_ * D_;  // B*T*H*D bf16

    // 0) converts
    hipLaunchKernelGGL(conv_f32_bf16, dim3(4096), dim3(256), 0, stream,
                       x, xb, (int)((size_t)B_ * T_ * C_ / 8));
    hipLaunchKernelGGL(tconv, dim3(64, 64), dim3(32, 8), 0, stream, Wq, wqt, 2048);
    hipLaunchKernelGGL(tconv, dim3(64, 16), dim3(32, 8), 0, stream, Wk, wkt, 512);
    hipLaunchKernelGGL(tconv, dim3(64, 16), dim3(32, 8), 0, stream, Wv, wvt, 512);
    hipLaunchKernelGGL(tconv, dim3(64, 64), dim3(32, 8), 0, stream, Wo, wot, 2048);

    // 1) QKV projection (8-phase 256^2 MFMA)
    hipLaunchKernelGGL(gemm_qkv8, dim3(192), dim3(512), 0, stream,
                       xb, wqt, wkt, wvt, qb, kb, vb);

    // 2) RoPE on q and k (contiguous -> one launch)
    hipLaunchKernelGGL(rope_bf16, dim3(B_ * (H_ + HKV_) * T_ * 32 / 256), dim3(256),
                       0, stream, qb);

    // 3) V transpose
    hipLaunchKernelGGL(transpose_v, dim3(T_ / 32, D_ / 32, B_ * HKV_), dim3(32, 8), 0, stream,
                       vb, vtb);

    // 4) flash attention v4 -> ab (bf16)
    hipLaunchKernelGGL(flash_attn_mfma, dim3(8, B_ * H_), dim3(512), 0, stream,
                       qb, kb, vtb, ab);

    // 5) output projection (8-phase 256^2 MFMA, fp32 out)
    hipLaunchKernelGGL(gemm_out8, dim3(128), dim3(512), 0, stream,
                       ab, wot, out);
}